// Round 7
// baseline (116.028 us; speedup 1.0000x reference)
//
#include <hip/hip_runtime.h>
#include <hip/hip_bf16.h>
#include <stdint.h>

typedef short bf16x8 __attribute__((ext_vector_type(8)));
typedef float f32x4 __attribute__((ext_vector_type(4)));
typedef float f32x16 __attribute__((ext_vector_type(16)));

#define DEVI static __device__ __forceinline__

constexpr int B_   = 32768;
constexpr int IN_  = 128;
constexpr int LF_  = 512;
constexpr int OUT_ = 32;

// ---- workspace layout (bytes) ----
// ltf: 32x32x16 B-frags, chunk(T,ks16)=T*32+ks; lane: n=T*32+(ln&31), k=ks*16+(ln>>5)*8
// w1f/w2f: 16x16x32 B-frags, chunk(t,ks32); lane: n=t*16+(ln&15), k=ks*32+(ln>>4)*8
// phig: per-block 64KB slab of phi in 32x32 A-frag chunk order:
//   elem phi[m][k] at slab + ((k>>4)*2 + (m>>5))*512 + ((m&31)+32*((k>>3)&1))*8 + (k&7)
constexpr size_t OFF_LTF = 0;                    // 524,288
constexpr size_t OFF_W1F = 524288;               // 131,072
constexpr size_t OFF_W2F = OFF_W1F + 131072;     // 49,152
constexpr size_t OFF_PHI = OFF_W2F + 49152;      // 33,554,432

DEVI short f2bs(float f) { __hip_bfloat16 h = __float2bfloat16(f); return *(short*)&h; }

DEVI float tanh_fast(float v) {
    float e = __expf(2.0f * v);
    return 1.0f - 2.0f * __builtin_amdgcn_rcpf(e + 1.0f);
}

DEVI void gl2lds16(const void* g, void* l) {
    __builtin_amdgcn_global_load_lds(
        (const __attribute__((address_space(1))) unsigned int*)g,
        (__attribute__((address_space(3))) unsigned int*)l,
        16, 0, 0);
}

DEVI bf16x8 fragGL(const __hip_bfloat16* base, int chunk, int ln) {
    return *(const bf16x8*)(base + ((size_t)chunk * 64 + ln) * 8);
}
DEVI f32x16 mfma32(bf16x8 a, bf16x8 b, f32x16 c) {
    return __builtin_amdgcn_mfma_f32_32x32x16_bf16(a, b, c, 0, 0, 0);
}

// x LDS: 64 rows x 16 chunks; slot = row*16 + ((k>>3) ^ (row&15))
DEVI bf16x8 xFrag(const char* p, int row, int kofs) {
    int c = (kofs >> 3) ^ (row & 15);
    return *(const bf16x8*)(p + (size_t)((row << 4) + c) * 16);
}
// phi 16x16 A-frag from A-frag-order LDS: m=mi*16+cl, k=ks*32+q*8
DEVI bf16x8 phi16(const char* p, int mi, int ks, int cl, int q) {
    int chunk = ks * 4 + (q >> 1) * 2 + (mi >> 1);
    int slot  = (mi & 1) * 16 + cl + 32 * (q & 1);
    return *(const bf16x8*)(p + ((size_t)chunk * 64 + slot) * 16);
}

// phase-3 K-loops, compile-time per wave: tiles {WV, 15-WV}, kstart16 = 2*T.
// A-frags: constant-offset ds_read_b128 at phiB + (ks*2+h)*1KB + ln*16.
template <int WV>
DEVI void p3loops(const char* phiB, const __hip_bfloat16* ltf, int ln,
                  f32x16 acc[2][2]) {
    constexpr int T1 = 15 - WV;
#pragma unroll
    for (int ks = 2 * WV; ks < 2 * T1; ++ks) {      // tile WV only
        bf16x8 b0 = fragGL(ltf, WV * 32 + ks, ln);
        bf16x8 a0 = *(const bf16x8*)(phiB + (size_t)(ks * 2 + 0) * 1024 + (size_t)ln * 16);
        bf16x8 a1 = *(const bf16x8*)(phiB + (size_t)(ks * 2 + 1) * 1024 + (size_t)ln * 16);
        acc[0][0] = mfma32(a0, b0, acc[0][0]);
        acc[0][1] = mfma32(a1, b0, acc[0][1]);
    }
#pragma unroll
    for (int ks = 2 * T1; ks < 32; ++ks) {          // both tiles
        bf16x8 b0 = fragGL(ltf, WV * 32 + ks, ln);
        bf16x8 b1 = fragGL(ltf, T1 * 32 + ks, ln);
        bf16x8 a0 = *(const bf16x8*)(phiB + (size_t)(ks * 2 + 0) * 1024 + (size_t)ln * 16);
        bf16x8 a1 = *(const bf16x8*)(phiB + (size_t)(ks * 2 + 1) * 1024 + (size_t)ln * 16);
        acc[0][0] = mfma32(a0, b0, acc[0][0]);
        acc[0][1] = mfma32(a1, b0, acc[0][1]);
        acc[1][0] = mfma32(a0, b1, acc[1][0]);
        acc[1][1] = mfma32(a1, b1, acc[1][1]);
    }
}

// ---------------- prep: fragment-order W1F / W2F / LTF ----------------
__global__ __launch_bounds__(256) void k_prep(
        const float* __restrict__ w1, const float* __restrict__ w2,
        const float* __restrict__ lv, const float* __restrict__ qb,
        __hip_bfloat16* __restrict__ w1f, __hip_bfloat16* __restrict__ w2f,
        __hip_bfloat16* __restrict__ ltf) {
    int cid = blockIdx.x * 256 + threadIdx.x;
    if (cid < 8192) {                       // W1F: nt(32) x ks(4) x ln(64)
        int ln = cid & 63, ks = (cid >> 6) & 3, nt = cid >> 8;
        int n = nt * 16 + (ln & 15), kb = ks * 32 + (ln >> 4) * 8;
        const float* src = w1 + (size_t)n * IN_ + kb;
        bf16x8 o;
#pragma unroll
        for (int i = 0; i < 8; ++i) o[i] = f2bs(src[i]);
        *(bf16x8*)(w1f + (size_t)cid * 8) = o;
    } else if (cid < 11264) {               // W2F: nt(3) x ks(16) x ln(64)
        int c2 = cid - 8192;
        int ln = c2 & 63, ks = (c2 >> 6) & 15, nt = c2 >> 10;
        int n = nt * 16 + (ln & 15), kb = ks * 32 + (ln >> 4) * 8;
        bf16x8 o;
#pragma unroll
        for (int i = 0; i < 8; ++i) {
            float v = (n < OUT_) ? w2[(size_t)n * LF_ + kb + i]
                                 : (n == OUT_ ? qb[kb + i] : 0.f);
            o[i] = f2bs(v);
        }
        *(bf16x8*)(w2f + (size_t)c2 * 8) = o;
    } else if (cid < 44032) {               // LTF: t(16) x ks(32) x ln(64)
        int c3 = cid - 11264;
        int ln = c3 & 63, ks = (c3 >> 6) & 31, t = c3 >> 11;
        int n = t * 32 + (ln & 31), kb = ks * 16 + (ln >> 5) * 8;
        bf16x8 o;
#pragma unroll
        for (int i = 0; i < 8; ++i) {
            int k = kb + i;                 // Lt[j=n][k] = L[k][j], zero for k<j
            o[i] = (k >= n) ? f2bs(lv[(size_t)k * (k + 1) / 2 + n]) : (short)0;
        }
        *(bf16x8*)(ltf + (size_t)c3 * 8) = o;
    }
}

// ---------------- k_phi: x -> phi (global, A-frag order) ----------------
// 512 threads, M=64/block, 512 blocks. LDS: 16KB x tile only.
__global__ __launch_bounds__(512, 4) void k_phi(
        const float* __restrict__ x, const __hip_bfloat16* __restrict__ w1f,
        const float* __restrict__ b1, __hip_bfloat16* __restrict__ phig) {
    __shared__ char stage[16384];
    const int tid = threadIdx.x, wv = tid >> 6, ln = tid & 63;
    const int cl = ln & 15, q = ln >> 4;
    const int m0 = blockIdx.x * 64;

    // stage x tile (64x128 fp32 -> bf16, swizzled)
#pragma unroll
    for (int it = 0; it < 2; ++it) {
        int slot = it * 512 + tid, row = slot >> 4, cg = slot & 15;
        const float4* p = (const float4*)(x + (size_t)(m0 + row) * IN_ + cg * 8);
        float4 u0 = p[0], u1 = p[1];
        bf16x8 pk;
        pk[0] = f2bs(u0.x); pk[1] = f2bs(u0.y); pk[2] = f2bs(u0.z); pk[3] = f2bs(u0.w);
        pk[4] = f2bs(u1.x); pk[5] = f2bs(u1.y); pk[6] = f2bs(u1.z); pk[7] = f2bs(u1.w);
        *(bf16x8*)(stage + (size_t)((row << 4) + (cg ^ (row & 15))) * 16) = pk;
    }
    __syncthreads();

    // phi^T = W1(A) x x^T(B): D rows = phi cols (q*4+r), D cols = batch rows (cl)
    f32x4 acc[4][4] = {};
#pragma unroll
    for (int ks = 0; ks < 4; ++ks) {
        bf16x8 a[4], wfr[4];
#pragma unroll
        for (int mi = 0; mi < 4; ++mi) a[mi] = xFrag(stage, mi * 16 + cl, ks * 32 + q * 8);
#pragma unroll
        for (int ni = 0; ni < 4; ++ni) wfr[ni] = fragGL(w1f, (4 * wv + ni) * 4 + ks, ln);
#pragma unroll
        for (int ni = 0; ni < 4; ++ni)
#pragma unroll
            for (int mi = 0; mi < 4; ++mi)
                acc[ni][mi] = __builtin_amdgcn_mfma_f32_16x16x32_bf16(
                    wfr[ni], a[mi], acc[ni][mi], 0, 0, 0);
    }
    // epilogue: tanh+bias, write straight to global in A-frag chunk order.
    // phi cols k0 = wv*64+ni*16+q*4..+3 for batch row m = mi*16+cl.
    __hip_bfloat16* slab = phig + (size_t)blockIdx.x * 32768;
#pragma unroll
    for (int ni = 0; ni < 4; ++ni) {
        float4 bb = *(const float4*)(b1 + wv * 64 + ni * 16 + q * 4);
#pragma unroll
        for (int mi = 0; mi < 4; ++mi) {
            short4 pk;
            pk.x = f2bs(tanh_fast(acc[ni][mi][0] + bb.x));
            pk.y = f2bs(tanh_fast(acc[ni][mi][1] + bb.y));
            pk.z = f2bs(tanh_fast(acc[ni][mi][2] + bb.z));
            pk.w = f2bs(tanh_fast(acc[ni][mi][3] + bb.w));
            size_t idx = (size_t)((wv * 4 + ni) * 2 + (mi >> 1)) * 512
                       + ((mi & 1) * 16 + cl + 32 * (q >> 1)) * 8 + (q & 1) * 4;
            *(short4*)(slab + idx) = pk;
        }
    }
}

// ---------------- k_piy: phi slab -> pi, vf ----------------
// 512 threads, M=64/block. LDS: phi 64KB + vfb/vfp 2.3KB -> 2 blocks/CU.
__global__ __launch_bounds__(512, 4) void k_piy(
        const __hip_bfloat16* __restrict__ phig, const __hip_bfloat16* __restrict__ w2f,
        const __hip_bfloat16* __restrict__ ltf, const float* __restrict__ qcp,
        float* __restrict__ pi, float* __restrict__ vf) {
    __shared__ char smem[67840];
    char*  phiB = smem;
    float* vfb  = (float*)(smem + 65536);
    float* vfp  = (float*)(smem + 65792);

    const int tid = threadIdx.x, wv = tid >> 6, ln = tid & 63;
    const int cl = ln & 15, q = ln >> 4;
    const int m0 = blockIdx.x * 64;
    const __hip_bfloat16* slab = phig + (size_t)blockIdx.x * 32768;

    // stage phi: 4096 chunks, 8 async rounds/wave, linear order
#pragma unroll
    for (int r = 0; r < 8; ++r) {
        int c = (r * 8 + wv) * 64;
        gl2lds16(slab + ((size_t)c + ln) * 8, phiB + (size_t)c * 16);
    }
    __syncthreads();

    // phase 2: pi = phi @ W2ext^T; 12 16x16 tiles over 8 waves
    {
        int ids[2] = { (wv < 4) ? 2 * wv : 8 + (wv - 4), (wv < 4) ? 2 * wv + 1 : -1 };
#pragma unroll
        for (int u = 0; u < 2; ++u) {
            int id = ids[u];
            if (id < 0) continue;
            int mi = id & 3, ni = id >> 2;
            f32x4 a2 = {};
#pragma unroll
            for (int ks = 0; ks < 16; ++ks) {
                bf16x8 a = phi16(phiB, mi, ks, cl, q);
                bf16x8 b = fragGL(w2f, ni * 16 + ks, ln);
                a2 = __builtin_amdgcn_mfma_f32_16x16x32_bf16(a, b, a2, 0, 0, 0);
            }
#pragma unroll
            for (int r = 0; r < 4; ++r) {
                int row = mi * 16 + q * 4 + r, col = ni * 16 + cl;
                if (col < OUT_)       pi[(size_t)(m0 + row) * OUT_ + col] = a2[r];
                else if (col == OUT_) vfb[row] = a2[r];   // phi.qb
            }
        }
    }

    // phase 3: y = rowsum((phi @ L)^2); 32x32x16, compile-time tile pairs
    {
        f32x16 acc[2][2] = {};
        switch (wv) {
            case 0: p3loops<0>(phiB, ltf, ln, acc); break;
            case 1: p3loops<1>(phiB, ltf, ln, acc); break;
            case 2: p3loops<2>(phiB, ltf, ln, acc); break;
            case 3: p3loops<3>(phiB, ltf, ln, acc); break;
            case 4: p3loops<4>(phiB, ltf, ln, acc); break;
            case 5: p3loops<5>(phiB, ltf, ln, acc); break;
            case 6: p3loops<6>(phiB, ltf, ln, acc); break;
            default: p3loops<7>(phiB, ltf, ln, acc); break;
        }
        // D (32x32): col = ln&31, row = (r&3)+8*(r>>2)+4*(ln>>5) [+32h]
#pragma unroll
        for (int h = 0; h < 2; ++h)
#pragma unroll
            for (int r = 0; r < 16; ++r) {
                float t0 = acc[0][h][r], t1 = acc[1][h][r];
                float s = t0 * t0 + t1 * t1;
                s += __shfl_xor(s, 1, 64);
                s += __shfl_xor(s, 2, 64);
                s += __shfl_xor(s, 4, 64);
                s += __shfl_xor(s, 8, 64);
                s += __shfl_xor(s, 16, 64);
                if ((ln & 31) == 0)
                    vfp[wv * 64 + h * 32 + (r & 3) + 8 * (r >> 2) + 4 * (ln >> 5)] = s;
            }
    }
    __syncthreads();
    if (tid < 64) {
        float v = vfb[tid] + qcp[0];
#pragma unroll
        for (int w = 0; w < 8; ++w) v += vfp[w * 64 + tid];
        vf[m0 + tid] = v;
    }
}

extern "C" void kernel_launch(void* const* d_in, const int* in_sizes, int n_in,
                              void* d_out, int out_size, void* d_ws, size_t ws_size,
                              hipStream_t stream) {
    const float* x  = (const float*)d_in[0];
    const float* w1 = (const float*)d_in[1];
    const float* b1 = (const float*)d_in[2];
    const float* w2 = (const float*)d_in[3];
    const float* lv = (const float*)d_in[4];
    const float* qb = (const float*)d_in[5];
    const float* qc = (const float*)d_in[6];

    char* ws = (char*)d_ws;
    __hip_bfloat16* ltf  = (__hip_bfloat16*)(ws + OFF_LTF);
    __hip_bfloat16* w1f  = (__hip_bfloat16*)(ws + OFF_W1F);
    __hip_bfloat16* w2f  = (__hip_bfloat16*)(ws + OFF_W2F);
    __hip_bfloat16* phig = (__hip_bfloat16*)(ws + OFF_PHI);

    float* pi = (float*)d_out;
    float* vf = pi + (size_t)B_ * OUT_;

    k_prep<<<172, 256, 0, stream>>>(w1, w2, lv, qb, w1f, w2f, ltf);
    k_phi <<<B_ / 64, 512, 0, stream>>>(x, w1f, b1, phig);
    k_piy <<<B_ / 64, 512, 0, stream>>>(phig, w2f, ltf, qc, pi, vf);
}

// Round 8
// 114.234 us; speedup vs baseline: 1.0157x; 1.0157x over previous
//
#include <hip/hip_runtime.h>
#include <hip/hip_bf16.h>
#include <stdint.h>

typedef short bf16x8 __attribute__((ext_vector_type(8)));
typedef float f32x4 __attribute__((ext_vector_type(4)));
typedef float f32x16 __attribute__((ext_vector_type(16)));

#define DEVI static __device__ __forceinline__

constexpr int B_   = 32768;
constexpr int IN_  = 128;
constexpr int LF_  = 512;
constexpr int OUT_ = 32;

// ---- workspace layout (bytes) ----
// ltf: 32x32x16 B-frags, chunk(T,ks16)=T*32+ks; lane: n=T*32+(ln&31), k=ks*16+(ln>>5)*8
// w1f/w2f: 16x16x32 B-frags, chunk(t,ks32); lane: n=t*16+(ln&15), k=ks*32+(ln>>4)*8
constexpr size_t OFF_LTF = 0;                    // 524,288
constexpr size_t OFF_W1F = 524288;               // 131,072
constexpr size_t OFF_W2F = OFF_W1F + 131072;     // 49,152

DEVI short f2bs(float f) { __hip_bfloat16 h = __float2bfloat16(f); return *(short*)&h; }

DEVI float tanh_fast(float v) {
    float e = __expf(2.0f * v);
    return 1.0f - 2.0f * __builtin_amdgcn_rcpf(e + 1.0f);
}

DEVI bf16x8 fragGL(const __hip_bfloat16* base, int chunk, int ln) {
    return *(const bf16x8*)(base + ((size_t)chunk * 64 + ln) * 8);
}
DEVI f32x16 mfma32(bf16x8 a, bf16x8 b, f32x16 c) {
    return __builtin_amdgcn_mfma_f32_32x32x16_bf16(a, b, c, 0, 0, 0);
}
DEVI f32x4 mfma16(bf16x8 a, bf16x8 b, f32x4 c) {
    return __builtin_amdgcn_mfma_f32_16x16x32_bf16(a, b, c, 0, 0, 0);
}

// x LDS: 64 rows x 16 chunks; slot = row*16 + ((k>>3) ^ (row&15))
DEVI bf16x8 xFrag(const char* p, int row, int kofs) {
    int c = (kofs >> 3) ^ (row & 15);
    return *(const bf16x8*)(p + (size_t)((row << 4) + c) * 16);
}
// phi STRIP buffer (64 rows x 128 cols, A-frag chunk order; 16 chunks of 1KB):
//   elem phi[m][kl] at chunk ((kl>>4)*2 + (m>>5)), slot (m&31)+32*((kl>>3)&1), byte (kl&7)*2
// 16x16 A-frag: m=mi*16+cl, kl=ksl32*32+q*8
DEVI bf16x8 phi16s(const char* p, int mi, int ksl, int cl, int q) {
    int chunk = ksl * 4 + (q >> 1) * 2 + (mi >> 1);
    int slot  = (mi & 1) * 16 + cl + 32 * (q & 1);
    return *(const bf16x8*)(p + ((size_t)chunk * 64 + slot) * 16);
}
// 32x32 A-frag: constant-offset read; chunk = i16*2 + h, lane slot = ln
DEVI bf16x8 phi32s(const char* p, int i16, int h, int ln) {
    return *(const bf16x8*)(p + ((size_t)(i16 * 2 + h) * 64 + ln) * 16);
}

// ---------------- prep: fragment-order W1F / W2F / LTF (verified R7) ----------------
__global__ __launch_bounds__(256) void k_prep(
        const float* __restrict__ w1, const float* __restrict__ w2,
        const float* __restrict__ lv, const float* __restrict__ qb,
        __hip_bfloat16* __restrict__ w1f, __hip_bfloat16* __restrict__ w2f,
        __hip_bfloat16* __restrict__ ltf) {
    int cid = blockIdx.x * 256 + threadIdx.x;
    if (cid < 8192) {                       // W1F: nt(32) x ks(4) x ln(64)
        int ln = cid & 63, ks = (cid >> 6) & 3, nt = cid >> 8;
        int n = nt * 16 + (ln & 15), kb = ks * 32 + (ln >> 4) * 8;
        const float* src = w1 + (size_t)n * IN_ + kb;
        bf16x8 o;
#pragma unroll
        for (int i = 0; i < 8; ++i) o[i] = f2bs(src[i]);
        *(bf16x8*)(w1f + (size_t)cid * 8) = o;
    } else if (cid < 11264) {               // W2F: nt(3) x ks(16) x ln(64)
        int c2 = cid - 8192;
        int ln = c2 & 63, ks = (c2 >> 6) & 15, nt = c2 >> 10;
        int n = nt * 16 + (ln & 15), kb = ks * 32 + (ln >> 4) * 8;
        bf16x8 o;
#pragma unroll
        for (int i = 0; i < 8; ++i) {
            float v = (n < OUT_) ? w2[(size_t)n * LF_ + kb + i]
                                 : (n == OUT_ ? qb[kb + i] : 0.f);
            o[i] = f2bs(v);
        }
        *(bf16x8*)(w2f + (size_t)c2 * 8) = o;
    } else if (cid < 44032) {               // LTF: t(16) x ks(32) x ln(64)
        int c3 = cid - 11264;
        int ln = c3 & 63, ks = (c3 >> 6) & 31, t = c3 >> 11;
        int n = t * 32 + (ln & 31), kb = ks * 16 + (ln >> 5) * 8;
        bf16x8 o;
#pragma unroll
        for (int i = 0; i < 8; ++i) {
            int k = kb + i;                 // Lt[j=n][k] = L[k][j], zero for k<j
            o[i] = (k >= n) ? f2bs(lv[(size_t)k * (k + 1) / 2 + n]) : (short)0;
        }
        *(bf16x8*)(ltf + (size_t)c3 * 8) = o;
    }
}

// ---------------- fused strip-pipelined kernel ----------------
// 512 thr (8 waves), M=64/block, grid 512.  LDS: x 16KB | phi dbuf 2x16KB |
// vfb 256B | vfp 2KB = 50.3KB -> 2+ blocks/CU.
// Strip pipeline: iter s runs P1(strip s) interleaved with P3(s-1)+P2(s-1).
__global__ __launch_bounds__(512, 4) void k_fused(
        const float* __restrict__ x, const __hip_bfloat16* __restrict__ w1f,
        const float* __restrict__ b1, const __hip_bfloat16* __restrict__ w2f,
        const __hip_bfloat16* __restrict__ ltf, const float* __restrict__ qcp,
        float* __restrict__ pi, float* __restrict__ vf) {
    __shared__ char smem[51456];
    char*  xs   = smem;
    char*  bufA = smem + 16384;   // strip parity 0
    char*  bufB = smem + 32768;   // strip parity 1
    float* vfb  = (float*)(smem + 49152);
    float* vfp  = (float*)(smem + 49408);

    const int tid = threadIdx.x, wv = tid >> 6, ln = tid & 63;
    const int cl = ln & 15, q = ln >> 4;
    const int m0 = blockIdx.x * 64;
    const int T1 = 15 - wv;                 // second phase-3 tile
    const int id0 = (wv < 4) ? 2 * wv : 8 + (wv - 4);
    const int id1 = (wv < 4) ? 2 * wv + 1 : -1;

    // persistent accumulators
    f32x16 acc3[2][2] = {};                 // P3: [tile][h]
    f32x4  acc2[2]    = {{0,0,0,0},{0,0,0,0}};  // P2: per id

    // ---- stage x tile (64x128 fp32 -> bf16, swizzled) ----
#pragma unroll
    for (int it = 0; it < 2; ++it) {
        int slot = it * 512 + tid, row = slot >> 4, cg = slot & 15;
        const float4* p = (const float4*)(x + (size_t)(m0 + row) * IN_ + cg * 8);
        float4 u0 = p[0], u1 = p[1];
        bf16x8 pk;
        pk[0] = f2bs(u0.x); pk[1] = f2bs(u0.y); pk[2] = f2bs(u0.z); pk[3] = f2bs(u0.w);
        pk[4] = f2bs(u1.x); pk[5] = f2bs(u1.y); pk[6] = f2bs(u1.z); pk[7] = f2bs(u1.w);
        *(bf16x8*)(xs + (size_t)((row << 4) + (cg ^ (row & 15))) * 16) = pk;
    }
    __syncthreads();

    // ---- strip pipeline ----
#pragma unroll
    for (int s = 0; s < 4; ++s) {
        char* wbuf = (s & 1) ? bufB : bufA;     // P1 writes strip s here
        char* rbuf = (s & 1) ? bufA : bufB;     // P3/P2 read strip s-1 here

        // ---- P1(strip s): phi cols [s*128, s*128+128); wave owns 16 cols ----
        {
            f32x4 p1a[4] = {};                  // [mi], D: row=phi-col, col=batch row
#pragma unroll
            for (int ks = 0; ks < 4; ++ks) {
                bf16x8 wfr = fragGL(w1f, (s * 8 + wv) * 4 + ks, ln);
#pragma unroll
                for (int mi = 0; mi < 4; ++mi) {
                    bf16x8 a = xFrag(xs, mi * 16 + cl, ks * 32 + q * 8);
                    p1a[mi] = mfma16(wfr, a, p1a[mi]);
                }
            }
            float4 bb = *(const float4*)(b1 + s * 128 + wv * 16 + q * 4);
#pragma unroll
            for (int mi = 0; mi < 4; ++mi) {
                int m = mi * 16 + cl;
                short4 pk;
                pk.x = f2bs(tanh_fast(p1a[mi][0] + bb.x));
                pk.y = f2bs(tanh_fast(p1a[mi][1] + bb.y));
                pk.z = f2bs(tanh_fast(p1a[mi][2] + bb.z));
                pk.w = f2bs(tanh_fast(p1a[mi][3] + bb.w));
                // chunk = wv*2 + (mi>>1); slot = (m&31)+32*(q>>1); byte + (q&1)*8
                *(short4*)(wbuf + (((size_t)(wv * 2 + (mi >> 1)) * 64
                            + (m & 31) + 32 * (q >> 1)) * 16) + (q & 1) * 8) = pk;
            }
        }

        if (s > 0) {
            const int sp = s - 1;
            // ---- P3(strip sp): ks16 global = sp*8 + i ----
#pragma unroll
            for (int i = 0; i < 8; ++i) {
                const int ks = sp * 8 + i;
                bool t0 = (ks >= 2 * wv), t1 = (ks >= 2 * T1);
                if (t0) {
                    bf16x8 a0 = phi32s(rbuf, i, 0, ln);
                    bf16x8 a1 = phi32s(rbuf, i, 1, ln);
                    bf16x8 b0 = fragGL(ltf, wv * 32 + ks, ln);
                    acc3[0][0] = mfma32(a0, b0, acc3[0][0]);
                    acc3[0][1] = mfma32(a1, b0, acc3[0][1]);
                    if (t1) {
                        bf16x8 b1f = fragGL(ltf, T1 * 32 + ks, ln);
                        acc3[1][0] = mfma32(a0, b1f, acc3[1][0]);
                        acc3[1][1] = mfma32(a1, b1f, acc3[1][1]);
                    }
                }
            }
            // ---- P2(strip sp): 4 ks32-steps ----
#pragma unroll
            for (int u = 0; u < 2; ++u) {
                int id = (u == 0) ? id0 : id1;
                if (id >= 0) {
                    int mi = id & 3, ni = id >> 2;
#pragma unroll
                    for (int ksl = 0; ksl < 4; ++ksl) {
                        bf16x8 a = phi16s(rbuf, mi, ksl, cl, q);
                        bf16x8 b = fragGL(w2f, ni * 16 + sp * 4 + ksl, ln);
                        acc2[u] = mfma16(a, b, acc2[u]);
                    }
                }
            }
        }
        __syncthreads();
    }

    // ---- tail: P3(3) + P2(3) on bufB (strip 3) ----
    {
        const int sp = 3;
#pragma unroll
        for (int i = 0; i < 8; ++i) {
            const int ks = sp * 8 + i;
            bool t1 = (ks >= 2 * T1);       // ks>=24 >= 2*wv always (wv<8 -> 2wv<16)
            bf16x8 a0 = phi32s(bufB, i, 0, ln);
            bf16x8 a1 = phi32s(bufB, i, 1, ln);
            bf16x8 b0 = fragGL(ltf, wv * 32 + ks, ln);
            acc3[0][0] = mfma32(a0, b0, acc3[0][0]);
            acc3[0][1] = mfma32(a1, b0, acc3[0][1]);
            if (t1) {
                bf16x8 b1f = fragGL(ltf, T1 * 32 + ks, ln);
                acc3[1][0] = mfma32(a0, b1f, acc3[1][0]);
                acc3[1][1] = mfma32(a1, b1f, acc3[1][1]);
            }
        }
#pragma unroll
        for (int u = 0; u < 2; ++u) {
            int id = (u == 0) ? id0 : id1;
            if (id >= 0) {
                int mi = id & 3, ni = id >> 2;
#pragma unroll
                for (int ksl = 0; ksl < 4; ++ksl) {
                    bf16x8 a = phi16s(bufB, mi, ksl, cl, q);
                    bf16x8 b = fragGL(w2f, ni * 16 + sp * 4 + ksl, ln);
                    acc2[u] = mfma16(a, b, acc2[u]);
                }
            }
        }
    }

    // ---- epilogues ----
    // P2 store: pi cols / vfb (qb col)
#pragma unroll
    for (int u = 0; u < 2; ++u) {
        int id = (u == 0) ? id0 : id1;
        if (id >= 0) {
            int mi = id & 3, ni = id >> 2;
#pragma unroll
            for (int r = 0; r < 4; ++r) {
                int row = mi * 16 + q * 4 + r, col = ni * 16 + cl;
                if (col < OUT_)       pi[(size_t)(m0 + row) * OUT_ + col] = acc2[u][r];
                else if (col == OUT_) vfb[row] = acc2[u][r];
            }
        }
    }
    // P3 reduce: D (32x32): col = ln&31, row = (r&3)+8*(r>>2)+4*(ln>>5) [+32h]
#pragma unroll
    for (int h = 0; h < 2; ++h)
#pragma unroll
        for (int r = 0; r < 16; ++r) {
            float t0 = acc3[0][h][r], t1 = acc3[1][h][r];
            float s = t0 * t0 + t1 * t1;
            s += __shfl_xor(s, 1, 64);
            s += __shfl_xor(s, 2, 64);
            s += __shfl_xor(s, 4, 64);
            s += __shfl_xor(s, 8, 64);
            s += __shfl_xor(s, 16, 64);
            if ((ln & 31) == 0)
                vfp[wv * 64 + h * 32 + (r & 3) + 8 * (r >> 2) + 4 * (ln >> 5)] = s;
        }
    __syncthreads();
    if (tid < 64) {
        float v = vfb[tid] + qcp[0];
#pragma unroll
        for (int w = 0; w < 8; ++w) v += vfp[w * 64 + tid];
        vf[m0 + tid] = v;
    }
}

extern "C" void kernel_launch(void* const* d_in, const int* in_sizes, int n_in,
                              void* d_out, int out_size, void* d_ws, size_t ws_size,
                              hipStream_t stream) {
    const float* x  = (const float*)d_in[0];
    const float* w1 = (const float*)d_in[1];
    const float* b1 = (const float*)d_in[2];
    const float* w2 = (const float*)d_in[3];
    const float* lv = (const float*)d_in[4];
    const float* qb = (const float*)d_in[5];
    const float* qc = (const float*)d_in[6];

    char* ws = (char*)d_ws;
    __hip_bfloat16* ltf = (__hip_bfloat16*)(ws + OFF_LTF);
    __hip_bfloat16* w1f = (__hip_bfloat16*)(ws + OFF_W1F);
    __hip_bfloat16* w2f = (__hip_bfloat16*)(ws + OFF_W2F);

    float* pi = (float*)d_out;
    float* vf = pi + (size_t)B_ * OUT_;

    k_prep <<<172, 256, 0, stream>>>(w1, w2, lv, qb, w1f, w2f, ltf);
    k_fused<<<B_ / 64, 512, 0, stream>>>(x, w1f, b1, w2f, ltf, qc, pi, vf);
}

// Round 9
// 110.974 us; speedup vs baseline: 1.0455x; 1.0294x over previous
//
#include <hip/hip_runtime.h>
#include <hip/hip_bf16.h>
#include <stdint.h>

typedef short bf16x8 __attribute__((ext_vector_type(8)));
typedef float f32x4 __attribute__((ext_vector_type(4)));

#define DEVI static __device__ __forceinline__

constexpr int B_   = 32768;
constexpr int IN_  = 128;
constexpr int LF_  = 512;
constexpr int OUT_ = 32;

// ---- workspace layout (bytes) ----
// B-side matrices in MFMA-fragment order: chunk c at base + c*1KB; lane ln
// reads +ln*16B (coalesced). ltf/w1f/w2f: 16x16x32 B-frags, chunk(tile,ks32);
// lane: n=tile*16+(ln&15), k=ks*32+(ln>>4)*8.
constexpr size_t OFF_LTF = 0;                    // 32 x 16 x 1KB = 524,288
constexpr size_t OFF_W1F = 524288;               // 32 x 4  x 1KB = 131,072
constexpr size_t OFF_W2F = OFF_W1F + 131072;     // 3  x 16 x 1KB = 49,152

DEVI short f2bs(float f) { __hip_bfloat16 h = __float2bfloat16(f); return *(short*)&h; }

DEVI float tanh_fast(float v) {
    float e = __expf(2.0f * v);
    return 1.0f - 2.0f * __builtin_amdgcn_rcpf(e + 1.0f);
}

DEVI bf16x8 fragGL(const __hip_bfloat16* base, int chunk, int ln) {
    return *(const bf16x8*)(base + ((size_t)chunk * 64 + ln) * 8);
}
DEVI f32x4 mfma16(bf16x8 a, bf16x8 b, f32x4 c) {
    return __builtin_amdgcn_mfma_f32_16x16x32_bf16(a, b, c, 0, 0, 0);
}

// x LDS: 64 rows x 16 chunks; slot = row*16 + ((k>>3) ^ (row&15))
DEVI bf16x8 xFrag(const char* p, int row, int kofs) {
    int c = (kofs >> 3) ^ (row & 15);
    return *(const bf16x8*)(p + (size_t)((row << 4) + c) * 16);
}
// phi: 4 slabs of 16KB (128 cols each), frag-native order:
//   elem phi[m][kl] (kl = col&127) at chunk (kl>>4)*2+(m>>5),
//   slot (m&31)+32*((kl>>3)&1), byte (kl&7)*2.
// 16x16 A-frag (m=mi*16+cl, kl=ksl*32+q*8): constant-offset b128 read.
DEVI bf16x8 phi16s(const char* slab, int mi, int ksl, int cl, int q) {
    int chunk = ksl * 4 + (q >> 1) * 2 + (mi >> 1);
    int slot  = (mi & 1) * 16 + cl + 32 * (q & 1);
    return *(const bf16x8*)(slab + ((size_t)chunk * 64 + slot) * 16);
}

// ---------------- prep: fragment-order W1F / W2F / LTF (R4, verified) ----------------
__global__ __launch_bounds__(256) void k_prep(
        const float* __restrict__ w1, const float* __restrict__ w2,
        const float* __restrict__ lv, const float* __restrict__ qb,
        __hip_bfloat16* __restrict__ w1f, __hip_bfloat16* __restrict__ w2f,
        __hip_bfloat16* __restrict__ ltf) {
    int cid = blockIdx.x * 256 + threadIdx.x;
    if (cid < 8192) {                       // W1F: nt(32) x ks(4) x ln(64)
        int ln = cid & 63, ks = (cid >> 6) & 3, nt = cid >> 8;
        int n = nt * 16 + (ln & 15), kb = ks * 32 + (ln >> 4) * 8;
        const float* src = w1 + (size_t)n * IN_ + kb;
        bf16x8 o;
#pragma unroll
        for (int i = 0; i < 8; ++i) o[i] = f2bs(src[i]);
        *(bf16x8*)(w1f + (size_t)cid * 8) = o;
    } else if (cid < 11264) {               // W2F: nt(3) x ks(16) x ln(64)
        int c2 = cid - 8192;
        int ln = c2 & 63, ks = (c2 >> 6) & 15, nt = c2 >> 10;
        int n = nt * 16 + (ln & 15), kb = ks * 32 + (ln >> 4) * 8;
        bf16x8 o;
#pragma unroll
        for (int i = 0; i < 8; ++i) {
            float v = (n < OUT_) ? w2[(size_t)n * LF_ + kb + i]
                                 : (n == OUT_ ? qb[kb + i] : 0.f);
            o[i] = f2bs(v);
        }
        *(bf16x8*)(w2f + (size_t)c2 * 8) = o;
    } else if (cid < 44032) {               // LTF: t(32) x ks(16) x ln(64)
        int c3 = cid - 11264;
        int ln = c3 & 63, ks = (c3 >> 6) & 15, t = c3 >> 10;
        int j = t * 16 + (ln & 15), kb = ks * 32 + (ln >> 4) * 8;
        bf16x8 o;
#pragma unroll
        for (int i = 0; i < 8; ++i) {
            int k = kb + i;                 // Lt[j][k] = L[k][j], zero for k<j
            o[i] = (k >= j) ? f2bs(lv[(size_t)k * (k + 1) / 2 + j]) : (short)0;
        }
        *(bf16x8*)(ltf + (size_t)c3 * 8) = o;
    }
}

// ---------------- fused: x -> phi(LDS slabs) -> vf, pi ----------------
// 512 thr (8 waves), M=64, grid 512. LDS: phi slabs 64KB | stage 16KB (x tile,
// aliased as vfb/vfp after phi barrier) = 80KB -> 2 blocks/CU = 16 waves/CU.
__global__ __launch_bounds__(512, 4) void k_fused(
        const float* __restrict__ x, const __hip_bfloat16* __restrict__ w1f,
        const float* __restrict__ b1, const __hip_bfloat16* __restrict__ w2f,
        const __hip_bfloat16* __restrict__ ltf, const float* __restrict__ qcp,
        float* __restrict__ pi, float* __restrict__ vf) {
    __shared__ char smem[81920];
    char*  phiS  = smem;                   // 4 slabs x 16KB
    char*  stage = smem + 65536;
    float* vfb   = (float*)stage;          // 64 f32 (alias; valid after phi barrier)
    float* vfp   = (float*)(stage + 256);  // 8x64 f32

    const int tid = threadIdx.x, wv = tid >> 6, ln = tid & 63;
    const int cl = ln & 15, q = ln >> 4;
    const int m0 = blockIdx.x * 64;

    // ---- phase 0: load+cast x tile (64x128 fp32 -> bf16) into LDS ----
#pragma unroll
    for (int it = 0; it < 2; ++it) {
        int slot = it * 512 + tid, row = slot >> 4, cg = slot & 15;
        const float4* p = (const float4*)(x + (size_t)(m0 + row) * IN_ + cg * 8);
        float4 u0 = p[0], u1 = p[1];
        bf16x8 pk;
        pk[0] = f2bs(u0.x); pk[1] = f2bs(u0.y); pk[2] = f2bs(u0.z); pk[3] = f2bs(u0.w);
        pk[4] = f2bs(u1.x); pk[5] = f2bs(u1.y); pk[6] = f2bs(u1.z); pk[7] = f2bs(u1.w);
        *(bf16x8*)(stage + (size_t)((row << 4) + (cg ^ (row & 15))) * 16) = pk;
    }
    __syncthreads();

    // ---- phase 1: phi^T = W1(A) x x^T(B); wave owns cols [wv*64, wv*64+64) ----
    // acc[ni][mi]: D rows (q*4+r) = phi cols, D cols (cl) = batch rows.
    {
        f32x4 acc[4][4] = {};
#pragma unroll
        for (int ks = 0; ks < 4; ++ks) {
            bf16x8 a[4], wfr[4];
#pragma unroll
            for (int mi = 0; mi < 4; ++mi) a[mi] = xFrag(stage, mi * 16 + cl, ks * 32 + q * 8);
#pragma unroll
            for (int ni = 0; ni < 4; ++ni) wfr[ni] = fragGL(w1f, (4 * wv + ni) * 4 + ks, ln);
#pragma unroll
            for (int ni = 0; ni < 4; ++ni)
#pragma unroll
                for (int mi = 0; mi < 4; ++mi)
                    acc[ni][mi] = __builtin_amdgcn_mfma_f32_16x16x32_bf16(
                        wfr[ni], a[mi], acc[ni][mi], 0, 0, 0);
        }
        // epilogue: tanh+bias, 4 consecutive phi cols -> one b64 store, frag-native slab
        char* slab = phiS + (size_t)(wv >> 1) * 16384;
#pragma unroll
        for (int ni = 0; ni < 4; ++ni) {
            float4 bb = *(const float4*)(b1 + wv * 64 + ni * 16 + q * 4);
            int chunk = (wv & 1) * 8 + ni * 2;          // + (mi>>1) below
#pragma unroll
            for (int mi = 0; mi < 4; ++mi) {
                short4 pk;
                pk.x = f2bs(tanh_fast(acc[ni][mi][0] + bb.x));
                pk.y = f2bs(tanh_fast(acc[ni][mi][1] + bb.y));
                pk.z = f2bs(tanh_fast(acc[ni][mi][2] + bb.z));
                pk.w = f2bs(tanh_fast(acc[ni][mi][3] + bb.w));
                int slot = (mi & 1) * 16 + cl + 32 * (q >> 1);
                *(short4*)(slab + ((size_t)(chunk + (mi >> 1)) * 64 + slot) * 16
                           + (q & 1) * 8) = pk;
            }
        }
    }
    __syncthreads();   // phi complete; x/stage dead -> vfb/vfp alias valid

    // ---- phase 3 (first): y = rowsum((phi @ L)^2); 16-chain mfma16 ----
    {
        const int tl[4] = { wv, 15 - wv, 16 + wv, 31 - wv };
        int kstart[4];
#pragma unroll
        for (int j = 0; j < 4; ++j) kstart[j] = (tl[j] * 16) & ~31;  // exact: Lt 0-padded
        const int kmin = kstart[0];
        f32x4 acc[4][4] = {};   // [tile][mi]
        for (int k0 = kmin; k0 < LF_; k0 += 32) {
            int ks = k0 >> 5;
            const char* slab = phiS + (size_t)(ks >> 2) * 16384;
            int ksl = ks & 3;
            bf16x8 a[4];
#pragma unroll
            for (int mi = 0; mi < 4; ++mi) a[mi] = phi16s(slab, mi, ksl, cl, q);
#pragma unroll
            for (int j = 0; j < 4; ++j) {
                if (k0 >= kstart[j]) {          // wave-uniform
                    bf16x8 b = fragGL(ltf, tl[j] * 16 + ks, ln);
#pragma unroll
                    for (int mi = 0; mi < 4; ++mi)
                        acc[j][mi] = __builtin_amdgcn_mfma_f32_16x16x32_bf16(
                            a[mi], b, acc[j][mi], 0, 0, 0);
                }
            }
        }
        // epilogue: sum u^2 over the wave's 64 cols, butterfly over col-lanes
#pragma unroll
        for (int mi = 0; mi < 4; ++mi)
#pragma unroll
            for (int r = 0; r < 4; ++r) {
                float s = 0.f;
#pragma unroll
                for (int j = 0; j < 4; ++j) { float t = acc[j][mi][r]; s += t * t; }
                s += __shfl_xor(s, 1, 64);
                s += __shfl_xor(s, 2, 64);
                s += __shfl_xor(s, 4, 64);
                s += __shfl_xor(s, 8, 64);
                if (cl == 0) vfp[wv * 64 + mi * 16 + q * 4 + r] = s;
            }
    }

    // ---- phase 2 (second): pi = phi @ W2ext^T; 12 tiles over 8 waves ----
    {
        int ids[2] = { (wv < 4) ? 2 * wv : 8 + (wv - 4), (wv < 4) ? 2 * wv + 1 : -1 };
#pragma unroll
        for (int u = 0; u < 2; ++u) {
            int id = ids[u];
            if (id < 0) continue;
            int mi = id & 3, ni = id >> 2;
            f32x4 a2 = {};
#pragma unroll
            for (int ks = 0; ks < 16; ++ks) {
                const char* slab = phiS + (size_t)(ks >> 2) * 16384;
                bf16x8 a = phi16s(slab, mi, ks & 3, cl, q);
                bf16x8 b = fragGL(w2f, ni * 16 + ks, ln);
                a2 = __builtin_amdgcn_mfma_f32_16x16x32_bf16(a, b, a2, 0, 0, 0);
            }
#pragma unroll
            for (int r = 0; r < 4; ++r) {
                int row = mi * 16 + q * 4 + r, col = ni * 16 + cl;
                if (col < OUT_)       pi[(size_t)(m0 + row) * OUT_ + col] = a2[r];
                else if (col == OUT_) vfb[row] = a2[r];   // phi.qb
            }
        }
    }
    __syncthreads();
    if (tid < 64) {
        float v = vfb[tid] + qcp[0];
#pragma unroll
        for (int w = 0; w < 8; ++w) v += vfp[w * 64 + tid];
        vf[m0 + tid] = v;
    }
}

extern "C" void kernel_launch(void* const* d_in, const int* in_sizes, int n_in,
                              void* d_out, int out_size, void* d_ws, size_t ws_size,
                              hipStream_t stream) {
    const float* x  = (const float*)d_in[0];
    const float* w1 = (const float*)d_in[1];
    const float* b1 = (const float*)d_in[2];
    const float* w2 = (const float*)d_in[3];
    const float* lv = (const float*)d_in[4];
    const float* qb = (const float*)d_in[5];
    const float* qc = (const float*)d_in[6];

    char* ws = (char*)d_ws;
    __hip_bfloat16* ltf = (__hip_bfloat16*)(ws + OFF_LTF);
    __hip_bfloat16* w1f = (__hip_bfloat16*)(ws + OFF_W1F);
    __hip_bfloat16* w2f = (__hip_bfloat16*)(ws + OFF_W2F);

    float* pi = (float*)d_out;
    float* vf = pi + (size_t)B_ * OUT_;

    k_prep <<<172, 256, 0, stream>>>(w1, w2, lv, qb, w1f, w2f, ltf);
    k_fused<<<B_ / 64, 512, 0, stream>>>(x, w1f, b1, w2f, ltf, qc, pi, vf);
}